// Round 8
// baseline (98.190 us; speedup 1.0000x reference)
//
#include <hip/hip_runtime.h>
#include <math.h>

#define NP 196   // patches per image
#define NC 10

// ---- DPP reductions ----
template<int CTRL>
__device__ __forceinline__ float dpp_sum_step(float x) {
    int t = __builtin_amdgcn_update_dpp(0, __float_as_int(x), CTRL, 0xf, 0xf, false);
    return x + __int_as_float(t);
}
__device__ __forceinline__ float row16_sum(float x) {   // row sums land in lanes 15/31/47/63
    x = dpp_sum_step<0x111>(x);
    x = dpp_sum_step<0x112>(x);
    x = dpp_sum_step<0x114>(x);
    x = dpp_sum_step<0x118>(x);
    return x;
}
__device__ __forceinline__ float bcast_lane(float x, int lane) {
    return __int_as_float(__builtin_amdgcn_readlane(__float_as_int(x), lane));
}
__device__ __forceinline__ float wave_sum(float x) {    // full-wave total, broadcast
    x = row16_sum(x);
    x = dpp_sum_step<0x142>(x);   // row_bcast:15
    x = dpp_sum_step<0x143>(x);   // row_bcast:31
    return bcast_lane(x, 63);
}

// One 4-qubit patch sim + MLP score, all in registers. Layer-0 variational
// RYs are folded into the data angles (RY(a)RY(b)|0> = RY(a+b)|0>).
__device__ __forceinline__ void patch_sim(
    const float* __restrict__ xb, int p,
    float vp0, float vp1, float vp2, float vp3,
    const float* __restrict__ c1, const float* __restrict__ s1,
    const float* __restrict__ w1, const float* __restrict__ b1,
    const float* __restrict__ w2, float b2v,
    float& m0, float& m1, float& m2, float& m3, float& sc)
{
    const int pr = p / 14;
    const int pc = p - pr * 14;
    const float* px = xb + (2 * pr) * 28 + 2 * pc;
    const float2 ra = *(const float2*)px;
    const float2 rb = *(const float2*)(px + 28);

    float cw[4], sw[4];
    __sincosf((ra.x + vp0) * 0.5f, &sw[0], &cw[0]);
    __sincosf((ra.y + vp1) * 0.5f, &sw[1], &cw[1]);
    __sincosf((rb.x + vp2) * 0.5f, &sw[2], &cw[2]);
    __sincosf((rb.y + vp3) * 0.5f, &sw[3], &cw[3]);

    // product state v[q0q1q2q3], wire0 = MSB (bit3)
    float t[4] = {cw[0]*cw[1], cw[0]*sw[1], sw[0]*cw[1], sw[0]*sw[1]};
    float u[4] = {cw[2]*cw[3], cw[2]*sw[3], sw[2]*cw[3], sw[2]*sw[3]};
    float v[16];
    #pragma unroll
    for (int i = 0; i < 16; i++) v[i] = t[i >> 2] * u[i & 3];

    // layer 0 CNOT chain (register renaming, free)
    #pragma unroll
    for (int i = 0; i < 16; i++)
        if ((i & 8) && !(i & 4)) { const float tm = v[i]; v[i] = v[i | 4]; v[i | 4] = tm; }
    #pragma unroll
    for (int i = 0; i < 16; i++)
        if ((i & 4) && !(i & 2)) { const float tm = v[i]; v[i] = v[i | 2]; v[i | 2] = tm; }
    #pragma unroll
    for (int i = 0; i < 16; i++)
        if ((i & 2) && !(i & 1)) { const float tm = v[i]; v[i] = v[i | 1]; v[i | 1] = tm; }

    // layer 1 RY butterflies (uniform angles), then CNOT chain
    #pragma unroll
    for (int w = 0; w < 4; w++) {
        const float c = c1[w], s = s1[w];
        const int m = 8 >> w;
        #pragma unroll
        for (int i = 0; i < 16; i++) {
            if ((i & m) == 0) {
                const float v0 = v[i], v1 = v[i | m];
                v[i]     = c * v0 - s * v1;
                v[i | m] = s * v0 + c * v1;
            }
        }
    }
    #pragma unroll
    for (int i = 0; i < 16; i++)
        if ((i & 8) && !(i & 4)) { const float tm = v[i]; v[i] = v[i | 4]; v[i | 4] = tm; }
    #pragma unroll
    for (int i = 0; i < 16; i++)
        if ((i & 4) && !(i & 2)) { const float tm = v[i]; v[i] = v[i | 2]; v[i | 2] = tm; }
    #pragma unroll
    for (int i = 0; i < 16; i++)
        if ((i & 2) && !(i & 1)) { const float tm = v[i]; v[i] = v[i | 1]; v[i | 1] = tm; }

    // Z expectations via hierarchical pairwise sums
    float pp[16];
    #pragma unroll
    for (int i = 0; i < 16; i++) pp[i] = v[i] * v[i];
    float e8[8], d8[8];
    #pragma unroll
    for (int j = 0; j < 8; j++) { e8[j] = pp[2*j] + pp[2*j+1]; d8[j] = pp[2*j] - pp[2*j+1]; }
    m3 = ((d8[0]+d8[1]) + (d8[2]+d8[3])) + ((d8[4]+d8[5]) + (d8[6]+d8[7]));
    float f4[4], g4[4];
    #pragma unroll
    for (int k = 0; k < 4; k++) { f4[k] = e8[2*k] + e8[2*k+1]; g4[k] = e8[2*k] - e8[2*k+1]; }
    m2 = (g4[0]+g4[1]) + (g4[2]+g4[3]);
    m1 = (f4[0]-f4[1]) + (f4[2]-f4[3]);
    m0 = (f4[0]+f4[1]) - (f4[2]+f4[3]);

    // MLP: score = b2 + w2 . relu(w1 . meas + b1); 2 independent accumulators
    float sA = b2v, sB = 0.f;
    #pragma unroll
    for (int j = 0; j < 64; j += 2) {
        float h0 = fmaf(w1[j*4 + 0], m0, fmaf(w1[j*4 + 1], m1,
                   fmaf(w1[j*4 + 2], m2, fmaf(w1[j*4 + 3], m3, b1[j]))));
        float h1 = fmaf(w1[j*4 + 4], m0, fmaf(w1[j*4 + 5], m1,
                   fmaf(w1[j*4 + 6], m2, fmaf(w1[j*4 + 7], m3, b1[j+1]))));
        sA = fmaf(w2[j],     fmaxf(h0, 0.f), sA);
        sB = fmaf(w2[j + 1], fmaxf(h1, 0.f), sB);
    }
    sc = sA + sB;
}

// Wave-per-image: block = 4 waves = 4 images, grid = B/4. Each lane runs two
// independent patch sims per pass (2 passes: {lane,lane+64},{lane+128,lane+192})
// giving 2-way ILP on every dependency chain. Softmax + logits are wave-local:
// zero LDS, zero barriers. No max-subtraction anywhere (scores/logits are O(1)
// for this problem's fixed weights; shift-invariance is exact).
__global__ __launch_bounds__(256, 4) void quanv_fused(
    const float* __restrict__ x,        // (B,28,28)
    const float* __restrict__ vparams,  // (2,4)
    const float* __restrict__ w1,       // (64,4)
    const float* __restrict__ b1,       // (64)
    const float* __restrict__ w2,       // (1,64)
    const float* __restrict__ b2,       // (1)
    const float* __restrict__ W,        // (10,784)
    const float* __restrict__ bias,     // (10)
    float* __restrict__ out,            // (B,10) log-softmax
    int Btot)
{
    const int tid  = threadIdx.x;
    const int lane = tid & 63;
    const int wv   = tid >> 6;
    const int img  = blockIdx.x * 4 + wv;
    if (img >= Btot) return;            // wave-uniform guard
    const float* xb = x + (size_t)img * 784;

    const float vp0 = vparams[0], vp1 = vparams[1];
    const float vp2 = vparams[2], vp3 = vparams[3];
    float c1[4], s1[4];
    #pragma unroll
    for (int w = 0; w < 4; w++) __sincosf(vparams[4 + w] * 0.5f, &s1[w], &c1[w]);
    const float b2v = b2[0];

    float r[11];                        // 10 unnormalized logits + sum(e)
    #pragma unroll
    for (int i = 0; i < 11; i++) r[i] = 0.f;

    #pragma unroll
    for (int pass = 0; pass < 2; pass++) {
        const int pA = lane + pass * 128;           // always < 196
        const int pB = pA + 64;
        const bool vB = (pB < NP);
        const int pBc = vB ? pB : NP - 1;

        float a0, a1, a2, a3, scA;
        float g0, g1, g2, g3, scB;
        patch_sim(xb, pA,  vp0, vp1, vp2, vp3, c1, s1, w1, b1, w2, b2v, a0, a1, a2, a3, scA);
        patch_sim(xb, pBc, vp0, vp1, vp2, vp3, c1, s1, w1, b1, w2, b2v, g0, g1, g2, g3, scB);

        const float eA = __expf(scA);               // no max-subtraction; scores O(1)
        const float eB = vB ? __expf(scB) : 0.f;
        const float wA0 = eA * a0, wA1 = eA * a1, wA2 = eA * a2, wA3 = eA * a3;
        const float wB0 = eB * g0, wB1 = eB * g1, wB2 = eB * g2, wB3 = eB * g3;

        #pragma unroll
        for (int o = 0; o < NC; o++) {
            const float4 WA = *(const float4*)(W + o * 784 + pA  * 4);
            const float4 WB = *(const float4*)(W + o * 784 + pBc * 4);
            r[o] += fmaf(wA0, WA.x, fmaf(wA1, WA.y, fmaf(wA2, WA.z, wA3 * WA.w)))
                  + fmaf(wB0, WB.x, fmaf(wB1, WB.y, fmaf(wB2, WB.z, wB3 * WB.w)));
        }
        r[10] += eA + eB;
    }

    // wave totals; lane i keeps total i (wave_sum broadcasts, cndmask selects)
    float esum = 0.f;
    float mytot = 0.f;
    #pragma unroll
    for (int i = 0; i < 11; i++) {
        const float tv = wave_sum(r[i]);
        if (i < NC) { if (lane == i) mytot = tv; }
        else        esum = tv;
    }

    const float rinv = __builtin_amdgcn_rcpf(esum);
    float logit = 0.f, ee = 0.f;
    if (lane < NC) {
        logit = fmaf(mytot, rinv, bias[lane]);
        ee = __expf(logit);             // logits O(1): no max-subtraction needed
    }
    const float ls  = row16_sum(ee);    // lanes 10..15 contribute 0
    const float lse = bcast_lane(ls, 15);
    if (lane < NC)
        out[(size_t)img * NC + lane] = logit - __logf(lse);
}

extern "C" void kernel_launch(void* const* d_in, const int* in_sizes, int n_in,
                              void* d_out, int out_size, void* d_ws, size_t ws_size,
                              hipStream_t stream) {
    const float* x       = (const float*)d_in[0];
    const float* vparams = (const float*)d_in[1];
    const float* w1      = (const float*)d_in[2];
    const float* b1      = (const float*)d_in[3];
    const float* w2      = (const float*)d_in[4];
    const float* b2      = (const float*)d_in[5];
    const float* W       = (const float*)d_in[6];
    const float* bias    = (const float*)d_in[7];
    float* out           = (float*)d_out;

    const int B = in_sizes[0] / 784;  // 28*28
    quanv_fused<<<(B + 3) / 4, 256, 0, stream>>>(x, vparams, w1, b1, w2, b2, W, bias, out, B);
}

// Round 9
// 95.624 us; speedup vs baseline: 1.0268x; 1.0268x over previous
//
#include <hip/hip_runtime.h>
#include <math.h>

#define NP 196   // patches per image
#define NC 10

// ---- DPP partial reduction: 4 row_shr steps; lanes 15/31/47/63 hold row-of-16 sums ----
template<int CTRL>
__device__ __forceinline__ float dpp_sum_step(float x) {
    int t = __builtin_amdgcn_update_dpp(0, __float_as_int(x), CTRL, 0xf, 0xf, false);
    return x + __int_as_float(t);
}
__device__ __forceinline__ float row16_sum(float x) {
    x = dpp_sum_step<0x111>(x);
    x = dpp_sum_step<0x112>(x);
    x = dpp_sum_step<0x114>(x);
    x = dpp_sum_step<0x118>(x);
    return x;
}
__device__ __forceinline__ float bcast_lane(float x, int lane) {
    return __int_as_float(__builtin_amdgcn_readlane(__float_as_int(x), lane));
}

// ===================== K1: one thread per patch (B*196 total) =====================
// Flat indexing: zero wasted lanes, no LDS, no barriers, minimal VGPRs -> high
// occupancy. Writes SoA planes: ws[q*total + g], q in {wm0,wm1,wm2,wm3,e}.
__global__ __launch_bounds__(256) void k_patch(
    const float* __restrict__ x,        // (B,28,28)
    const float* __restrict__ vparams,  // (2,4)
    const float* __restrict__ w1,       // (64,4)
    const float* __restrict__ b1,       // (64)
    const float* __restrict__ w2,       // (1,64)
    const float* __restrict__ b2,       // (1)
    float* __restrict__ ws,             // 5 planes of `total` floats
    int total)
{
    const int g = blockIdx.x * 256 + threadIdx.x;
    if (g >= total) return;
    const int img = g / NP;             // compile-time-constant divisor -> magic mul
    const int p   = g - img * NP;

    const int pr = p / 14;
    const int pc = p - pr * 14;
    const float* px = x + (size_t)img * 784 + (2 * pr) * 28 + 2 * pc;
    const float2 ra = *(const float2*)px;
    const float2 rb = *(const float2*)(px + 28);

    // layer-0 variational RYs folded into data angles (RY(a)RY(b)|0> = RY(a+b)|0>)
    float cw[4], sw[4];
    __sincosf((ra.x + vparams[0]) * 0.5f, &sw[0], &cw[0]);
    __sincosf((ra.y + vparams[1]) * 0.5f, &sw[1], &cw[1]);
    __sincosf((rb.x + vparams[2]) * 0.5f, &sw[2], &cw[2]);
    __sincosf((rb.y + vparams[3]) * 0.5f, &sw[3], &cw[3]);

    // product state v[q0q1q2q3], wire0 = MSB (bit3)
    float t[4] = {cw[0]*cw[1], cw[0]*sw[1], sw[0]*cw[1], sw[0]*sw[1]};
    float u[4] = {cw[2]*cw[3], cw[2]*sw[3], sw[2]*cw[3], sw[2]*sw[3]};
    float v[16];
    #pragma unroll
    for (int i = 0; i < 16; i++) v[i] = t[i >> 2] * u[i & 3];

    // layer 0 CNOT chain (register renaming, free)
    #pragma unroll
    for (int i = 0; i < 16; i++)
        if ((i & 8) && !(i & 4)) { const float tm = v[i]; v[i] = v[i | 4]; v[i | 4] = tm; }
    #pragma unroll
    for (int i = 0; i < 16; i++)
        if ((i & 4) && !(i & 2)) { const float tm = v[i]; v[i] = v[i | 2]; v[i | 2] = tm; }
    #pragma unroll
    for (int i = 0; i < 16; i++)
        if ((i & 2) && !(i & 1)) { const float tm = v[i]; v[i] = v[i | 1]; v[i | 1] = tm; }

    // layer 1: RY butterflies (uniform angles via scalar loads), then CNOT chain
    #pragma unroll
    for (int w = 0; w < 4; w++) {
        float c, s;
        __sincosf(vparams[4 + w] * 0.5f, &s, &c);
        const int m = 8 >> w;
        #pragma unroll
        for (int i = 0; i < 16; i++) {
            if ((i & m) == 0) {
                const float v0 = v[i], v1 = v[i | m];
                v[i]     = c * v0 - s * v1;
                v[i | m] = s * v0 + c * v1;
            }
        }
    }
    #pragma unroll
    for (int i = 0; i < 16; i++)
        if ((i & 8) && !(i & 4)) { const float tm = v[i]; v[i] = v[i | 4]; v[i | 4] = tm; }
    #pragma unroll
    for (int i = 0; i < 16; i++)
        if ((i & 4) && !(i & 2)) { const float tm = v[i]; v[i] = v[i | 2]; v[i | 2] = tm; }
    #pragma unroll
    for (int i = 0; i < 16; i++)
        if ((i & 2) && !(i & 1)) { const float tm = v[i]; v[i] = v[i | 1]; v[i | 1] = tm; }

    // Z expectations via hierarchical pairwise sums
    float pp[16];
    #pragma unroll
    for (int i = 0; i < 16; i++) pp[i] = v[i] * v[i];
    float e8[8], d8[8];
    #pragma unroll
    for (int j = 0; j < 8; j++) { e8[j] = pp[2*j] + pp[2*j+1]; d8[j] = pp[2*j] - pp[2*j+1]; }
    const float m3v = ((d8[0]+d8[1]) + (d8[2]+d8[3])) + ((d8[4]+d8[5]) + (d8[6]+d8[7]));
    float f4[4], g4[4];
    #pragma unroll
    for (int k = 0; k < 4; k++) { f4[k] = e8[2*k] + e8[2*k+1]; g4[k] = e8[2*k] - e8[2*k+1]; }
    const float m2v = (g4[0]+g4[1]) + (g4[2]+g4[3]);
    const float m1v = (f4[0]-f4[1]) + (f4[2]-f4[3]);
    const float m0v = (f4[0]+f4[1]) - (f4[2]+f4[3]);

    // MLP: score = b2 + w2 . relu(w1 . meas + b1); 4 independent accumulators
    float sc0 = b2[0], sc1 = 0.f, sc2 = 0.f, sc3 = 0.f;
    #pragma unroll
    for (int j = 0; j < 64; j += 4) {
        float h0 = fmaf(w1[j*4 +  0], m0v, fmaf(w1[j*4 +  1], m1v,
                   fmaf(w1[j*4 +  2], m2v, fmaf(w1[j*4 +  3], m3v, b1[j]))));
        float h1 = fmaf(w1[j*4 +  4], m0v, fmaf(w1[j*4 +  5], m1v,
                   fmaf(w1[j*4 +  6], m2v, fmaf(w1[j*4 +  7], m3v, b1[j+1]))));
        float h2 = fmaf(w1[j*4 +  8], m0v, fmaf(w1[j*4 +  9], m1v,
                   fmaf(w1[j*4 + 10], m2v, fmaf(w1[j*4 + 11], m3v, b1[j+2]))));
        float h3 = fmaf(w1[j*4 + 12], m0v, fmaf(w1[j*4 + 13], m1v,
                   fmaf(w1[j*4 + 14], m2v, fmaf(w1[j*4 + 15], m3v, b1[j+3]))));
        sc0 = fmaf(w2[j],     fmaxf(h0, 0.f), sc0);
        sc1 = fmaf(w2[j + 1], fmaxf(h1, 0.f), sc1);
        sc2 = fmaf(w2[j + 2], fmaxf(h2, 0.f), sc2);
        sc3 = fmaf(w2[j + 3], fmaxf(h3, 0.f), sc3);
    }
    const float sc = (sc0 + sc1) + (sc2 + sc3);

    // unnormalized softmax weight (no max-subtraction; scores are O(1))
    const float e = __expf(sc);
    ws[0 * (size_t)total + g] = e * m0v;
    ws[1 * (size_t)total + g] = e * m1v;
    ws[2 * (size_t)total + g] = e * m2v;
    ws[3 * (size_t)total + g] = e * m3v;
    ws[4 * (size_t)total + g] = e;
}

// ===================== K2: block-per-image reduction =====================
// 11 parallel reductions (10 unnormalized logits + sum(e)) via row16 DPP +
// one 11x16 LDS combine + single barrier + wave-0 log-softmax epilogue.
__global__ __launch_bounds__(256, 4) void k_reduce(
    const float* __restrict__ ws,       // 5 planes of `total`
    const float* __restrict__ W,        // (10,784)
    const float* __restrict__ bias,     // (10)
    float* __restrict__ out,            // (B,10)
    int total)
{
    __shared__ float s_part[11][16];

    const int tid  = threadIdx.x;
    const int b    = blockIdx.x;
    const int lane = tid & 63;
    const int wv   = tid >> 6;
    const int pt   = (tid < NP) ? tid : NP - 1;
    const float sel = (tid < NP) ? 1.f : 0.f;
    const size_t base = (size_t)b * NP + pt;

    const float wm0 = sel * ws[0 * (size_t)total + base];
    const float wm1 = sel * ws[1 * (size_t)total + base];
    const float wm2 = sel * ws[2 * (size_t)total + base];
    const float wm3 = sel * ws[3 * (size_t)total + base];
    const float e   = sel * ws[4 * (size_t)total + base];

    float r[11];
    #pragma unroll
    for (int o = 0; o < NC; o++) {
        const float4 Wv = *(const float4*)(W + o * 784 + pt * 4);
        r[o] = fmaf(wm0, Wv.x, fmaf(wm1, Wv.y, fmaf(wm2, Wv.z, wm3 * Wv.w)));
    }
    r[10] = e;

    #pragma unroll
    for (int i = 0; i < 11; i++) r[i] = row16_sum(r[i]);
    if ((lane & 15) == 15) {
        const int row = (wv << 2) | (lane >> 4);
        #pragma unroll
        for (int i = 0; i < 11; i++) s_part[i][row] = r[i];
    }
    __syncthreads();

    if (wv == 0) {
        float tot = 0.f;
        if (lane < 11) {
            const float4* q = (const float4*)s_part[lane];
            const float4 a = q[0], c = q[1], d = q[2], g = q[3];
            tot = (((a.x+a.y) + (a.z+a.w)) + ((c.x+c.y) + (c.z+c.w)))
                + (((d.x+d.y) + (d.z+d.w)) + ((g.x+g.y) + (g.z+g.w)));
        }
        const float esum = bcast_lane(tot, 10);
        const float rinv = __builtin_amdgcn_rcpf(esum);
        float logit = 0.f, ee = 0.f;
        if (lane < NC) {
            logit = fmaf(tot, rinv, bias[lane]);
            ee = __expf(logit);          // logits O(1): no max-subtraction needed
        }
        const float ls  = row16_sum(ee); // lanes 10..15 contribute 0
        const float lse = bcast_lane(ls, 15);
        if (lane < NC)
            out[(size_t)b * NC + lane] = logit - __logf(lse);
    }
}

extern "C" void kernel_launch(void* const* d_in, const int* in_sizes, int n_in,
                              void* d_out, int out_size, void* d_ws, size_t ws_size,
                              hipStream_t stream) {
    const float* x       = (const float*)d_in[0];
    const float* vparams = (const float*)d_in[1];
    const float* w1      = (const float*)d_in[2];
    const float* b1      = (const float*)d_in[3];
    const float* w2      = (const float*)d_in[4];
    const float* b2      = (const float*)d_in[5];
    const float* W       = (const float*)d_in[6];
    const float* bias    = (const float*)d_in[7];
    float* out           = (float*)d_out;
    float* ws            = (float*)d_ws;

    const int B = in_sizes[0] / 784;    // 28*28
    const int total = B * NP;

    k_patch<<<(total + 255) / 256, 256, 0, stream>>>(x, vparams, w1, b1, w2, b2, ws, total);
    k_reduce<<<B, 256, 0, stream>>>(ws, W, bias, out, total);
}